// Round 16
// baseline (40.380 us; speedup 1.0000x reference)
//
#include <hip/hip_runtime.h>
#include <hip/hip_fp16.h>

// Local attention block: 40^3 volume, C=64, 4 heads of hd=16, 3x3x3 window,
// replicate padding, residual add. f32 in/out.
//
// All intermediates FP16. QKV head-planar [head][N][16ch] (round-14 win).
// Kernel 0: pack W f32 -> f16 [192][64] (Q rows pre-scaled 1/4) + f32 bias.
// Kernel 1: proj via MFMA 16x16x32 f16 -- NO LDS, NO barrier: A-fragments
//           read direct from the packed W table (L1-resident 24.5 KB; each
//           wave's fragment load covers a contiguous 2 KB row-block), x
//           B-fragments direct to registers.
// Kernel 2: attention (round-14 exact): block = (4x8x8 tile, ONE head),
//           512 threads, thread-pair per voxel (8ch halves), DPP xor-1
//           pair reduce, packed-f16 hfma2, e/16 PV scaling.

#define NVOX 64000   // 40*40*40
#define DIM 40
#define CCH 64
#define HEADS 4
#define HD 16
#define HPL (NVOX * HD)   // head-plane stride in f16 elements

// attn tile geometry (one head per block)
#define ATZ 4
#define ATY 8
#define ATX 8
#define ANH 600           // 6*10*10 halo voxels

typedef __attribute__((ext_vector_type(8))) _Float16 f16x8;
typedef __attribute__((ext_vector_type(4))) float f32x4;

__device__ __forceinline__ unsigned pkh(float a, float b) {
    __half2 h = __floats2half2_rn(a, b);
    return *reinterpret_cast<unsigned*>(&h);
}
__device__ __forceinline__ __half2 u2h(unsigned u) {
    __half2 h; *reinterpret_cast<unsigned*>(&h) = u; return h;
}

__device__ __forceinline__ int xcd_swz(int b) {   // bijective, 1000 % 8 == 0
    return (b & 7) * 125 + (b >> 3);
}
__device__ __forceinline__ int xcd_swz500(int b) { // bijective for 500 (m204)
    const int xcd = b & 7, loc = b >> 3;           // q=62, r=4
    return (xcd < 4 ? xcd * 63 : 252 + (xcd - 4) * 62) + loc;
}

__global__ __launch_bounds__(256) void pack_kernel(
    const float* __restrict__ Wq, const float* __restrict__ bq,
    const float* __restrict__ Wk, const float* __restrict__ bk,
    const float* __restrict__ Wv, const float* __restrict__ bv,
    unsigned short* __restrict__ Wp, float* __restrict__ bp)
{
    const int t = blockIdx.x * 256 + threadIdx.x;
    if (t < 12288) {
        const int r = t >> 6, c = t & 63;
        const float val = (r < 64)  ? 0.25f * Wq[r * 64 + c]
                        : (r < 128) ? Wk[(r - 64) * 64 + c]
                                    : Wv[(r - 128) * 64 + c];
        const __half hv = __float2half_rn(val);
        Wp[t] = *reinterpret_cast<const unsigned short*>(&hv);
    }
    if (t < 192) {
        bp[t] = (t < 64)  ? 0.25f * bq[t]
              : (t < 128) ? bk[t - 64]
                          : bv[t - 128];
    }
}

__global__ __launch_bounds__(512) void proj_mfma(
    const float* __restrict__ x,
    const unsigned short* __restrict__ Wp, const float* __restrict__ bp,
    unsigned short* __restrict__ Qg, unsigned short* __restrict__ Kg,
    unsigned short* __restrict__ Vg)
{
    const int tid = threadIdx.x;
    const int bid = xcd_swz500((int)blockIdx.x);
    const int n0 = bid * 128;                // 500 * 128 = 64000

    const int lane = tid & 63;
    const int wv   = tid >> 6;               // 8 waves -> 8 voxel-16-tiles
    const int l15  = lane & 15;
    const int l4   = lane >> 4;
    const int vox  = wv * 16 + l15;
    const int n    = n0 + vox;               // D col = lane&15 -> voxel

    // ---- x B-fragments direct to registers (coalesced 64B segments) ----
    float xf[16];
    #pragma unroll
    for (int j = 0; j < 8; ++j)
        xf[j] = x[(l4 * 8 + j) * NVOX + n];
    #pragma unroll
    for (int j = 0; j < 8; ++j)
        xf[8 + j] = x[(32 + l4 * 8 + j) * NVOX + n];

    union { unsigned u[4]; f16x8 v; } U0, U1;
    #pragma unroll
    for (int p = 0; p < 4; ++p) {
        U0.u[p] = pkh(xf[2 * p], xf[2 * p + 1]);
        U1.u[p] = pkh(xf[8 + 2 * p], xf[9 + 2 * p]);
    }
    const f16x8 bx0 = U0.v, bx1 = U1.v;

    #pragma unroll
    for (int rb = 0; rb < 12; ++rb) {
        const int row = rb * 16 + l15;       // A row, k-chunks l4 / l4+4
        // Direct global fragment loads: wave covers a contiguous 2 KB
        // row-block of the 24.5 KB packed-W table (L1-resident).
        const f16x8 a0 = *reinterpret_cast<const f16x8*>(&Wp[row * 64 + l4 * 8]);
        const f16x8 a1 = *reinterpret_cast<const f16x8*>(&Wp[row * 64 + 32 + l4 * 8]);

        f32x4 acc = {0.f, 0.f, 0.f, 0.f};
        acc = __builtin_amdgcn_mfma_f32_16x16x32_f16(a0, bx0, acc, 0, 0, 0);
        acc = __builtin_amdgcn_mfma_f32_16x16x32_f16(a1, bx1, acc, 0, 0, 0);

        const int r0 = rb * 16 + l4 * 4;     // D rows r0..r0+3 for this lane
        const float4 bs = *reinterpret_cast<const float4*>(&bp[r0]);

        // Head-planar store: matrix = rb>>2, head = rb&3, ch = l4*4.
        unsigned short* og = (rb < 4) ? Qg : (rb < 8) ? Kg : Vg;
        const size_t dst = (size_t)(rb & 3) * HPL + (size_t)n * HD + l4 * 4;
        *reinterpret_cast<uint2*>(&og[dst]) =
            make_uint2(pkh(acc[0] + bs.x, acc[1] + bs.y),
                       pkh(acc[2] + bs.z, acc[3] + bs.w));
    }
}

__global__ __launch_bounds__(512, 8) void attn_kernel(
    const float* __restrict__ x,
    const unsigned short* __restrict__ Qg, const unsigned short* __restrict__ Kg,
    const unsigned short* __restrict__ Vg,
    float* __restrict__ out)
{
    // LDS per matrix: [half(8ch)][600 halo voxels][8 f16] -> 16 B lane stride
    __shared__ __align__(16) unsigned short Kl[2 * ANH * 8];   // 19200 B
    __shared__ __align__(16) unsigned short Vl[2 * ANH * 8];   // 19200 B

    const int tid = threadIdx.x;
    const int bid = xcd_swz((int)blockIdx.x);   // 250 tiles x 4 heads
    const int h    = bid & 3;
    const int tile = bid >> 2;
    const int tx = tile % 5;
    const int ty = (tile / 5) % 5;
    const int tz = tile / 25;
    const int z0 = tz * ATZ - 1, y0 = ty * ATY - 1, x0 = tx * ATX - 1;

    const unsigned short* Qh = Qg + (size_t)h * HPL;
    const unsigned short* Kh = Kg + (size_t)h * HPL;
    const unsigned short* Vh = Vg + (size_t)h * HPL;

    // ---- Thread pair shares a voxel; part selects the 8-channel half ----
    const int vox  = tid >> 1;             // 0..255
    const int part = tid & 1;              // 0: ch 0-7, 1: ch 8-15
    const int lz = vox >> 6, ly = (vox >> 3) & 7, lx = vox & 7;
    const int gz = tz * ATZ + lz, gy = ty * ATY + ly, gx = tx * ATX + lx;
    const int n = (gz * DIM + gy) * DIM + gx;

    // Q: this thread's 8 channels (16 B), issued before staging. Dense plane.
    const uint4 qw = *reinterpret_cast<const uint4*>(
        &Qh[(size_t)n * HD + part * 8]);

    // ---- Stage K+V halo: 600 items, 32 B of K + 32 B of V each (dense) ----
    #pragma unroll
    for (int i = 0; i < 2; ++i) {
        const int ml = tid + i * 512;
        if (ml < ANH) {
            const int hz = ml / 100; const int r = ml - hz * 100;
            const int hy = r / 10;   const int hx = r - hy * 10;
            const int sz = min(max(z0 + hz, 0), DIM - 1);
            const int sy = min(max(y0 + hy, 0), DIM - 1);
            const int sx = min(max(x0 + hx, 0), DIM - 1);
            const size_t base = (size_t)((sz * DIM + sy) * DIM + sx) * HD;
            const uint4 k0 = *reinterpret_cast<const uint4*>(&Kh[base]);
            const uint4 k1 = *reinterpret_cast<const uint4*>(&Kh[base + 8]);
            const uint4 v0 = *reinterpret_cast<const uint4*>(&Vh[base]);
            const uint4 v1 = *reinterpret_cast<const uint4*>(&Vh[base + 8]);
            *reinterpret_cast<uint4*>(&Kl[ml * 8])           = k0;
            *reinterpret_cast<uint4*>(&Kl[ANH * 8 + ml * 8]) = k1;
            *reinterpret_cast<uint4*>(&Vl[ml * 8])           = v0;
            *reinterpret_cast<uint4*>(&Vl[ANH * 8 + ml * 8]) = v1;
        }
    }
    __syncthreads();

    __half2 qh[4];
    qh[0] = u2h(qw.x); qh[1] = u2h(qw.y); qh[2] = u2h(qw.z); qh[3] = u2h(qw.w);

    const int mlc = (lz + 1) * 100 + (ly + 1) * 10 + (lx + 1);
    const uint4* kb = reinterpret_cast<const uint4*>(Kl) + part * ANH + mlc;
    const uint4* vb = reinterpret_cast<const uint4*>(Vl) + part * ANH + mlc;

    float s = 0.0f;
    __half2 av[4];
    #pragma unroll
    for (int i = 0; i < 4; ++i) av[i] = __float2half2_rn(0.0f);

    #pragma unroll
    for (int dz = -1; dz <= 1; ++dz) {
        #pragma unroll
        for (int dy = -1; dy <= 1; ++dy) {
            #pragma unroll
            for (int dx = -1; dx <= 1; ++dx) {
                const int off = dz * 100 + dy * 10 + dx;
                const uint4 k = kb[off];           // this part's 8 ch (4x f16x2)

                __half2 acc2 = __hmul2(qh[0], u2h(k.x));
                acc2 = __hfma2(qh[1], u2h(k.y), acc2);
                acc2 = __hfma2(qh[2], u2h(k.z), acc2);
                acc2 = __hfma2(qh[3], u2h(k.w), acc2);
                const float lgh = __low2float(acc2) + __high2float(acc2);
                // pair-reduce: DPP quad_perm [1,0,3,2] swaps lane^1 (pure VALU)
                const int oth = __builtin_amdgcn_mov_dpp(
                    __float_as_int(lgh), 0xB1, 0xF, 0xF, true);
                const float lg = lgh + __int_as_float(oth);

                // max-free softmax: logits ~N(0,1); e^|lg| far from f32 limit
                const float e = __expf(lg);
                s += e;
                // accumulate with e/16: f16 headroom to logit ~13.9
                const __half2 e2 = __float2half2_rn(e * 0.0625f);

                const uint4 v = vb[off];
                av[0] = __hfma2(e2, u2h(v.x), av[0]);
                av[1] = __hfma2(e2, u2h(v.y), av[1]);
                av[2] = __hfma2(e2, u2h(v.z), av[2]);
                av[3] = __hfma2(e2, u2h(v.w), av[3]);
            }
        }
    }

    const float rs = 16.0f / s;              // undo the 1/16 scaling
    const int cb = h * HD + part * 8;
    #pragma unroll
    for (int i = 0; i < 4; ++i) {
        const size_t i0 = (size_t)(cb + 2 * i) * NVOX + n;
        const size_t i1 = (size_t)(cb + 2 * i + 1) * NVOX + n;
        out[i0] = x[i0] + __low2float(av[i]) * rs;
        out[i1] = x[i1] + __high2float(av[i]) * rs;
    }
}

extern "C" void kernel_launch(void* const* d_in, const int* in_sizes, int n_in,
                              void* d_out, int out_size, void* d_ws, size_t ws_size,
                              hipStream_t stream) {
    const float* x  = (const float*)d_in[0];
    // d_in[1] = cemb (unused by the reference)
    const float* Wq = (const float*)d_in[2];
    const float* bq = (const float*)d_in[3];
    const float* Wk = (const float*)d_in[4];
    const float* bk = (const float*)d_in[5];
    const float* Wv = (const float*)d_in[6];
    const float* bv = (const float*)d_in[7];
    float* out = (float*)d_out;

    unsigned short* Qg = (unsigned short*)d_ws;        // f16 [4][N][16]
    unsigned short* Kg = Qg + (size_t)NVOX * CCH;      // f16 [4][N][16]
    unsigned short* Vg = Kg + (size_t)NVOX * CCH;      // f16 [4][N][16]
    unsigned short* Wp = Vg + (size_t)NVOX * CCH;      // f16 [192][64]
    float* bp          = (float*)(Wp + 192 * 64);      // f32 [192]

    pack_kernel<<<dim3(48), dim3(256), 0, stream>>>(
        Wq, bq, Wk, bk, Wv, bv, Wp, bp);
    proj_mfma<<<dim3(500), dim3(512), 0, stream>>>(
        x, Wp, bp, Qg, Kg, Vg);
    attn_kernel<<<dim3(1000), dim3(512), 0, stream>>>(
        x, Qg, Kg, Vg, out);
}

// Round 17
// 28.539 us; speedup vs baseline: 1.4149x; 1.4149x over previous
//
#include <hip/hip_runtime.h>
#include <hip/hip_fp16.h>

// Local attention block: 40^3 volume, C=64, 4 heads of hd=16, 3x3x3 window,
// replicate padding, residual add. f32 in/out.
//
// All intermediates FP16. QKV head-planar [head][N][16ch] (round-14 win).
// Kernel 1: proj via MFMA 16x16x32 f16 (round-14 exact): 500 blocks x 512
//           threads; W f32->f16 staged to LDS per block (measured faster
//           than "L1-resident" global fragment reads -- round-16 ledger);
//           x B-fragments direct to registers before the W barrier.
// Kernel 2: attention, block = (8x8x8 tile, ONE head), 1024 threads:
//           thread-pair per voxel (8ch halves). Halo 10^3 = 1000 vox,
//           K+V LDS = 64.0 KB -> 2 blocks/CU x 16 waves = 32 waves/CU
//           (same occupancy as round-14, staging traffic x0.83).
//           DPP xor-1 pair reduce, packed-f16 hfma2, e/16 PV scaling.

#define NVOX 64000   // 40*40*40
#define DIM 40
#define CCH 64
#define HEADS 4
#define HD 16
#define HPL (NVOX * HD)   // head-plane stride in f16 elements

// attn tile geometry (one head per block)
#define ATS 8             // 8x8x8 own tile
#define ANH 1000          // 10*10*10 halo voxels

typedef __attribute__((ext_vector_type(8))) _Float16 f16x8;
typedef __attribute__((ext_vector_type(4))) float f32x4;

__device__ __forceinline__ unsigned pkh(float a, float b) {
    __half2 h = __floats2half2_rn(a, b);
    return *reinterpret_cast<unsigned*>(&h);
}
__device__ __forceinline__ __half2 u2h(unsigned u) {
    __half2 h; *reinterpret_cast<unsigned*>(&h) = u; return h;
}

__device__ __forceinline__ int xcd_swz500(int b) { // bijective for 500 (m204)
    const int xcd = b & 7, loc = b >> 3;           // q=62, r=4
    return (xcd < 4 ? xcd * 63 : 252 + (xcd - 4) * 62) + loc;
}

__global__ __launch_bounds__(512) void proj_mfma(
    const float* __restrict__ x,
    const float* __restrict__ Wq, const float* __restrict__ bq,
    const float* __restrict__ Wk, const float* __restrict__ bk,
    const float* __restrict__ Wv, const float* __restrict__ bv,
    unsigned short* __restrict__ Qg, unsigned short* __restrict__ Kg,
    unsigned short* __restrict__ Vg)
{
    // W LDS: [chunk(8ch)][192 rows][8 f16] -> 16 B lane stride (conflict-free)
    __shared__ __align__(16) unsigned short Wl[8 * 192 * 8];  // 24576 B
    __shared__ __align__(16) float bl[192];                   //   768 B

    const int tid = threadIdx.x;
    const int bid = xcd_swz500((int)blockIdx.x);
    const int n0 = bid * 128;                // 500 * 128 = 64000

    const int lane = tid & 63;
    const int wv   = tid >> 6;               // 8 waves -> 8 voxel-16-tiles
    const int l15  = lane & 15;
    const int l4   = lane >> 4;
    const int vox  = wv * 16 + l15;
    const int n    = n0 + vox;               // D col = lane&15 -> voxel

    // ---- x B-fragments direct to registers; issue BEFORE the W barrier ----
    float xf[16];
    #pragma unroll
    for (int j = 0; j < 8; ++j)
        xf[j] = x[(l4 * 8 + j) * NVOX + n];          // 64B-segment coalesced
    #pragma unroll
    for (int j = 0; j < 8; ++j)
        xf[8 + j] = x[(32 + l4 * 8 + j) * NVOX + n];

    // ---- Stage W + bias: 1536 items over 512 threads (3 each) ----
    #pragma unroll
    for (int i = 0; i < 3; ++i) {
        const int item = tid + i * 512;
        const int row = item % 192, chunk = item / 192;
        const float* Wsrc; float sc; int r;
        if (row < 64)       { Wsrc = Wq; sc = 0.25f; r = row; }
        else if (row < 128) { Wsrc = Wk; sc = 1.0f;  r = row - 64; }
        else                { Wsrc = Wv; sc = 1.0f;  r = row - 128; }
        const float4 f0 = *reinterpret_cast<const float4*>(&Wsrc[r * 64 + chunk * 8]);
        const float4 f1 = *reinterpret_cast<const float4*>(&Wsrc[r * 64 + chunk * 8 + 4]);
        *reinterpret_cast<uint4*>(&Wl[(chunk * 192 + row) * 8]) =
            make_uint4(pkh(sc * f0.x, sc * f0.y), pkh(sc * f0.z, sc * f0.w),
                       pkh(sc * f1.x, sc * f1.y), pkh(sc * f1.z, sc * f1.w));
    }
    if (tid < 192) {
        const float* bsrc; float sc; int r;
        if (tid < 64)       { bsrc = bq; sc = 0.25f; r = tid; }
        else if (tid < 128) { bsrc = bk; sc = 1.0f;  r = tid - 64; }
        else                { bsrc = bv; sc = 1.0f;  r = tid - 128; }
        bl[tid] = sc * bsrc[r];
    }

    // Pack x fragments while W loads are in flight.
    union { unsigned u[4]; f16x8 v; } U0, U1;
    #pragma unroll
    for (int p = 0; p < 4; ++p) {
        U0.u[p] = pkh(xf[2 * p], xf[2 * p + 1]);
        U1.u[p] = pkh(xf[8 + 2 * p], xf[9 + 2 * p]);
    }
    const f16x8 bx0 = U0.v, bx1 = U1.v;

    __syncthreads();

    #pragma unroll
    for (int rb = 0; rb < 12; ++rb) {
        const int row = rb * 16 + l15;       // A row, k-chunks l4 / l4+4
        const f16x8 a0 = *reinterpret_cast<const f16x8*>(&Wl[(l4 * 192 + row) * 8]);
        const f16x8 a1 = *reinterpret_cast<const f16x8*>(&Wl[((l4 + 4) * 192 + row) * 8]);

        f32x4 acc = {0.f, 0.f, 0.f, 0.f};
        acc = __builtin_amdgcn_mfma_f32_16x16x32_f16(a0, bx0, acc, 0, 0, 0);
        acc = __builtin_amdgcn_mfma_f32_16x16x32_f16(a1, bx1, acc, 0, 0, 0);

        const int r0 = rb * 16 + l4 * 4;     // D rows r0..r0+3 for this lane
        const float4 bs = *reinterpret_cast<const float4*>(&bl[r0]);

        // Head-planar store: matrix = rb>>2, head = rb&3, ch = l4*4.
        unsigned short* og = (rb < 4) ? Qg : (rb < 8) ? Kg : Vg;
        const size_t dst = (size_t)(rb & 3) * HPL + (size_t)n * HD + l4 * 4;
        *reinterpret_cast<uint2*>(&og[dst]) =
            make_uint2(pkh(acc[0] + bs.x, acc[1] + bs.y),
                       pkh(acc[2] + bs.z, acc[3] + bs.w));
    }
}

__global__ __launch_bounds__(1024, 8) void attn_kernel(
    const float* __restrict__ x,
    const unsigned short* __restrict__ Qg, const unsigned short* __restrict__ Kg,
    const unsigned short* __restrict__ Vg,
    float* __restrict__ out)
{
    // LDS per matrix: [half(8ch)][1000 halo voxels][8 f16] -> 16 B lane stride
    __shared__ __align__(16) unsigned short Kl[2 * ANH * 8];   // 32000 B
    __shared__ __align__(16) unsigned short Vl[2 * ANH * 8];   // 32000 B

    const int tid = threadIdx.x;
    const int bid = xcd_swz500((int)blockIdx.x);   // 125 tiles x 4 heads
    const int h    = bid & 3;
    const int tile = bid >> 2;
    const int tx = tile % 5;
    const int ty = (tile / 5) % 5;
    const int tz = tile / 25;
    const int z0 = tz * ATS - 1, y0 = ty * ATS - 1, x0 = tx * ATS - 1;

    const unsigned short* Qh = Qg + (size_t)h * HPL;
    const unsigned short* Kh = Kg + (size_t)h * HPL;
    const unsigned short* Vh = Vg + (size_t)h * HPL;

    // ---- Thread pair shares a voxel; part selects the 8-channel half ----
    const int vox  = tid >> 1;             // 0..511
    const int part = tid & 1;              // 0: ch 0-7, 1: ch 8-15
    const int lz = vox >> 6, ly = (vox >> 3) & 7, lx = vox & 7;
    const int gz = tz * ATS + lz, gy = ty * ATS + ly, gx = tx * ATS + lx;
    const int n = (gz * DIM + gy) * DIM + gx;

    // Q: this thread's 8 channels (16 B), issued before staging. Dense plane.
    const uint4 qw = *reinterpret_cast<const uint4*>(
        &Qh[(size_t)n * HD + part * 8]);

    // ---- Stage K+V halo: 1000 items, 32 B of K + 32 B of V each (dense) ----
    if (tid < ANH) {
        const int ml = tid;
        const int hz = ml / 100; const int r = ml - hz * 100;
        const int hy = r / 10;   const int hx = r - hy * 10;
        const int sz = min(max(z0 + hz, 0), DIM - 1);
        const int sy = min(max(y0 + hy, 0), DIM - 1);
        const int sx = min(max(x0 + hx, 0), DIM - 1);
        const size_t base = (size_t)((sz * DIM + sy) * DIM + sx) * HD;
        const uint4 k0 = *reinterpret_cast<const uint4*>(&Kh[base]);
        const uint4 k1 = *reinterpret_cast<const uint4*>(&Kh[base + 8]);
        const uint4 v0 = *reinterpret_cast<const uint4*>(&Vh[base]);
        const uint4 v1 = *reinterpret_cast<const uint4*>(&Vh[base + 8]);
        *reinterpret_cast<uint4*>(&Kl[ml * 8])           = k0;
        *reinterpret_cast<uint4*>(&Kl[ANH * 8 + ml * 8]) = k1;
        *reinterpret_cast<uint4*>(&Vl[ml * 8])           = v0;
        *reinterpret_cast<uint4*>(&Vl[ANH * 8 + ml * 8]) = v1;
    }
    __syncthreads();

    __half2 qh[4];
    qh[0] = u2h(qw.x); qh[1] = u2h(qw.y); qh[2] = u2h(qw.z); qh[3] = u2h(qw.w);

    const int mlc = (lz + 1) * 100 + (ly + 1) * 10 + (lx + 1);
    const uint4* kb = reinterpret_cast<const uint4*>(Kl) + part * ANH + mlc;
    const uint4* vb = reinterpret_cast<const uint4*>(Vl) + part * ANH + mlc;

    float s = 0.0f;
    __half2 av[4];
    #pragma unroll
    for (int i = 0; i < 4; ++i) av[i] = __float2half2_rn(0.0f);

    #pragma unroll
    for (int dz = -1; dz <= 1; ++dz) {
        #pragma unroll
        for (int dy = -1; dy <= 1; ++dy) {
            #pragma unroll
            for (int dx = -1; dx <= 1; ++dx) {
                const int off = dz * 100 + dy * 10 + dx;
                const uint4 k = kb[off];           // this part's 8 ch (4x f16x2)

                __half2 acc2 = __hmul2(qh[0], u2h(k.x));
                acc2 = __hfma2(qh[1], u2h(k.y), acc2);
                acc2 = __hfma2(qh[2], u2h(k.z), acc2);
                acc2 = __hfma2(qh[3], u2h(k.w), acc2);
                const float lgh = __low2float(acc2) + __high2float(acc2);
                // pair-reduce: DPP quad_perm [1,0,3,2] swaps lane^1 (pure VALU)
                const int oth = __builtin_amdgcn_mov_dpp(
                    __float_as_int(lgh), 0xB1, 0xF, 0xF, true);
                const float lg = lgh + __int_as_float(oth);

                // max-free softmax: logits ~N(0,1); e^|lg| far from f32 limit
                const float e = __expf(lg);
                s += e;
                // accumulate with e/16: f16 headroom to logit ~13.9
                const __half2 e2 = __float2half2_rn(e * 0.0625f);

                const uint4 v = vb[off];
                av[0] = __hfma2(e2, u2h(v.x), av[0]);
                av[1] = __hfma2(e2, u2h(v.y), av[1]);
                av[2] = __hfma2(e2, u2h(v.z), av[2]);
                av[3] = __hfma2(e2, u2h(v.w), av[3]);
            }
        }
    }

    const float rs = 16.0f / s;              // undo the 1/16 scaling
    const int cb = h * HD + part * 8;
    #pragma unroll
    for (int i = 0; i < 4; ++i) {
        const size_t i0 = (size_t)(cb + 2 * i) * NVOX + n;
        const size_t i1 = (size_t)(cb + 2 * i + 1) * NVOX + n;
        out[i0] = x[i0] + __low2float(av[i]) * rs;
        out[i1] = x[i1] + __high2float(av[i]) * rs;
    }
}

extern "C" void kernel_launch(void* const* d_in, const int* in_sizes, int n_in,
                              void* d_out, int out_size, void* d_ws, size_t ws_size,
                              hipStream_t stream) {
    const float* x  = (const float*)d_in[0];
    // d_in[1] = cemb (unused by the reference)
    const float* Wq = (const float*)d_in[2];
    const float* bq = (const float*)d_in[3];
    const float* Wk = (const float*)d_in[4];
    const float* bk = (const float*)d_in[5];
    const float* Wv = (const float*)d_in[6];
    const float* bv = (const float*)d_in[7];
    float* out = (float*)d_out;

    unsigned short* Qg = (unsigned short*)d_ws;        // f16 [4][N][16]
    unsigned short* Kg = Qg + (size_t)NVOX * CCH;      // f16 [4][N][16]
    unsigned short* Vg = Kg + (size_t)NVOX * CCH;      // f16 [4][N][16]

    proj_mfma<<<dim3(500), dim3(512), 0, stream>>>(
        x, Wq, bq, Wk, bk, Wv, bv, Qg, Kg, Vg);
    attn_kernel<<<dim3(500), dim3(1024), 0, stream>>>(
        x, Qg, Kg, Vg, out);
}